// Round 12
// baseline (1564.505 us; speedup 1.0000x reference)
//
#include <hip/hip_runtime.h>
#include <math.h>

#define IMG_H 256
#define IMG_W 256
#define IMG_SZ (IMG_H * IMG_W)
#define NP 49      /* C*p*p patch vector length */
#define HP 250     /* H - p + 1 */
#define NB 4096    /* groups per image = 64*64 */
#define NCAND 1369 /* 37*37 */
#define VRAD 18
#define CENTER (VRAD * 37 + VRAD)
#define NIMG 2
#define YSTR 52    /* patch row stride: 208B, 16B aligned */
#define WSTR 55    /* bm window stride: odd -> conflict-free */
#define PXR 43     /* pixel-region rows per denoise block */
#define PXC 56     /* pixel-region cols per denoise block */

// Map aligned-patch coordinates (253x253, after align_corners with s=4 on a
// 250x250 grid) to original patch coordinates. Returns false for inf slots.
__device__ __forceinline__ bool align_map(int r, int c, int& ro, int& co) {
    if (r < 0 || r > 252 || c < 0 || c > 252) return false;
    if (r == 252) {
        if (c == 252) { ro = 249; co = 249; return true; }
        if (c <= 248 && (c & 3) == 0) { ro = 249; co = c; return true; }
        return false;
    }
    if (c == 252) {
        if (r <= 248 && (r & 3) == 0) { ro = r; co = 249; return true; }
        return false;
    }
    if (r >= 250 || c >= 250) return false;
    if (r == 249) {
        if (c == 249) return false;
        if ((c & 3) == 0) return false;
        ro = 249; co = c; return true;
    }
    if (c == 249) {
        if ((r & 3) == 0) return false;
        ro = r; co = 249; return true;
    }
    ro = r; co = c; return true;
}

__global__ void zero_kernel(float* __restrict__ p, int total) {
    int i = blockIdx.x * blockDim.x + threadIdx.x;
    if (i < total) p[i] = 0.0f;
}

// acc holds interleaved (num, weight) pairs per pixel.
__global__ void div_kernel(const float* __restrict__ acc, float* __restrict__ out, int total) {
    int i = blockIdx.x * blockDim.x + threadIdx.x;
    if (i < total) out[i] = acc[2 * i] / acc[2 * i + 1];
}

// 4 reference patches per 256-thread block (one wave each), sharing one staged
// union window. refp in registers; center forced during fill; selection via
// barrier-free shfl butterfly over per-lane top-2 caches.
template <int M>
__global__ __launch_bounds__(256) void bm_kernel(const float* __restrict__ img,
                                                 int* __restrict__ idx_out) {
    __shared__ float win[43 * WSTR];
    __shared__ float dist[4][NCAND];
    const int llb = blockIdx.x, kk = blockIdx.y, n = blockIdx.z;
    const float* im = img + (size_t)n * IMG_SZ;
    const int t = threadIdx.x;
    const int w = t >> 6, lane = t & 63;
    const int ll = 4 * llb + w;
    const int rr = (kk < 63) ? 4 * kk : 249;
    const int cc = (ll < 63) ? 4 * ll : 249;
    const int ar0 = 4 * kk, ac0 = 4 * ll;
    const int acb = 16 * llb;
    const int row0 = max(0, ar0 - VRAD), col0 = max(0, acb - VRAD);
    const int row1 = min(IMG_H - 1, ar0 + VRAD + 6);
    const int col1 = min(IMG_W - 1, acb + 12 + VRAD + 6);
    const int nr = row1 - row0 + 1, nc = col1 - col0 + 1;
    for (int e = t; e < nr * nc; e += 256) {
        int r = e / nc, c = e % nc;
        win[r * WSTR + c] = im[(row0 + r) * IMG_W + col0 + c];
    }
    __syncthreads();
    float rf[NP];
    {
        const float* rb = &win[(rr - row0) * WSTR + (cc - col0)];
#pragma unroll
        for (int ki = 0; ki < 7; ++ki)
#pragma unroll
            for (int kj = 0; kj < 7; ++kj) rf[ki * 7 + kj] = rb[ki * WSTR + kj];
    }
    float* dw = dist[w];
    for (int cand = lane; cand < NCAND; cand += 64) {
        const int dr = cand / 37 - VRAD, dc = cand % 37 - VRAD;
        int ro, co;
        float d;
        if (align_map(ar0 + dr, ac0 + dc, ro, co)) {
            const float* base = &win[(ro - row0) * WSTR + (co - col0)];
            float s = 0.f;
#pragma unroll
            for (int ki = 0; ki < 7; ++ki)
#pragma unroll
                for (int kj = 0; kj < 7; ++kj) {
                    float df = base[ki * WSTR + kj] - rf[ki * 7 + kj] + 1e-6f;
                    s = fmaf(df, df, s);
                }
            d = sqrtf(s);
        } else {
            d = INFINITY;
        }
        if (cand == CENTER) d = -1.0f;  // center always wins sel 0
        dw[cand] = d;
    }
    __syncthreads();
    // per-lane top-2 over the strided bucket (ascending scan => ties keep low idx)
    float v1 = INFINITY, v2 = INFINITY;
    int i1 = NCAND, i2 = NCAND;
    for (int c = lane; c < NCAND; c += 64) {
        float v = dw[c];
        if (v < v1) { v2 = v1; i2 = i1; v1 = v; i1 = c; }
        else if (v < v2) { v2 = v; i2 = c; }
    }
    int* out = idx_out + (size_t)((n * 64 + kk) * 64 + ll) * M;
    for (int sel = 0; sel < M; ++sel) {
        float gv = v1;
        int gi = i1;
#pragma unroll
        for (int off = 32; off; off >>= 1) {
            float vv = __shfl_xor(gv, off);
            int ii = __shfl_xor(gi, off);
            if (vv < gv || (vv == gv && ii < gi)) { gv = vv; gi = ii; }
        }
        if (lane == 0) {
            int dr = gi / 37 - VRAD, dc = gi % 37 - VRAD;
            out[sel] = min(rr + dr, 249) * HP + min(cc + dc, 249);
        }
        if ((gi & 63) == lane) {  // owner pops its cache; rescan only if exhausted
            dw[gi] = INFINITY;
            v1 = v2; i1 = i2; v2 = INFINITY; i2 = NCAND;
            if (i1 == NCAND) {
                for (int c = lane; c < NCAND; c += 64) {
                    float v = dw[c];
                    if (v < v1) { v2 = v1; i2 = i1; v1 = v; i1 = c; }
                    else if (v < v2) { v2 = v; i2 = c; }
                }
            }
        }
    }
}

// 128 threads (2 waves); G=4 column-adjacent groups processed sequentially per
// block (same kk, ll = 4*llb..+3). theta = I - c*A^-1 in BOTH rounds. Per
// group: LDS union SU = [packed-L | Ys rows]; Gram slot-distributed; Cholesky
// wave0-only register rows (d^2 form); solves wave0 = M identity cols
// (weights), wave1 = 49 Y cols (X_hat), uniform broadcast float4 L reads.
// Contributions accumulate into an LDS 43x56 pixel region (ds-atomics) whose
// row origin is anchored at ROW_REF (= min(4kk,249), the clamp target), then
// ONE global atomic pair per nonzero region pixel at flush.
template <int M, bool R2>
__global__ __launch_bounds__(128, 2) void denoise_kernel(
    const float* __restrict__ y, const float* __restrict__ xsrc,
    const int* __restrict__ idx, const float* __restrict__ sigma_p,
    float* __restrict__ accPix) {
    constexpr int PADM = (M + 3) & ~3;  // 56 for M=55, 20 for M=18
    constexpr int NCH = PADM / 4;
    constexpr int TPK = M * (M + 1) / 2;
    constexpr int NS = (TPK + 127) / 128;
    // packed row offset (floats), each row 16B aligned: sum_{k<i} roundup4(k+1)
    struct RO { static constexpr int f(int i) {
        int a = i >> 2, b = i & 3; return 8 * a * (a + 1) + 4 * (a + 1) * b; } };
    constexpr int LSZ = RO::f(PADM);
    constexpr int YOFF = LSZ;            // Ys rows live after the packed L
    constexpr int UN = LSZ + M * YSTR;   // union size (floats)
    __shared__ __align__(16) float SU[UN];
    __shared__ float Nl[PXR * PXC];
    __shared__ float Wl[PXR * PXC];
    __shared__ float cbuf[64];
    __shared__ __align__(16) float rdiag[PADM];
    __shared__ float wsh[M];
    __shared__ int gix[M];
    const int llb = blockIdx.x, kk = blockIdx.y, n = blockIdx.z;
    const int t = threadIdx.x;
    const int lane = t & 63, wv = t >> 6;
    // Region anchored at the REFERENCE row (clamp target), not the aligned row:
    // patch rows span [rr-18, min(rr+18,249)], rr = (kk<63)?4kk:249 -> 43 rows.
    const int rrRef = (kk < 63) ? 4 * kk : 249;
    const int row0p = max(0, rrRef - VRAD);
    const int col0p = max(0, 16 * llb - VRAD);
    const float* im = y + (size_t)n * IMG_SZ;
    const float* xim = xsrc + (size_t)n * IMG_SZ;
    const float sg = sigma_p[0];
    const float cns = 49.f * sg * sg;
    // zero the pixel-region accumulators
    for (int e = t; e < PXR * PXC; e += 128) { Nl[e] = 0.f; Wl[e] = 0.f; }
    // slot decode (fixed across groups)
    int siR[NS], sjR[NS];
#pragma unroll
    for (int s = 0; s < NS; ++s) {
        int e = t + 128 * s;
        if (e < TPK) {
            int i = (int)((sqrtf(8.f * e + 1.f) - 1.f) * 0.5f);
            while ((i + 1) * (i + 2) / 2 <= e) ++i;
            while (i * (i + 1) / 2 > e) --i;
            siR[s] = i;
            sjR[s] = e - i * (i + 1) / 2;
        } else {
            siR[s] = -1;
            sjR[s] = 0;
        }
    }
#pragma unroll 1
    for (int g = 0; g < 4; ++g) {
        __syncthreads();  // SU/gix safe to overwrite (also covers Nl/Wl zero on g=0)
        if (t < M) gix[t] = idx[(size_t)(n * NB + kk * 64 + 4 * llb + g) * M + t];
        __syncthreads();
        // --- stage Gram source rows (R1: Ys at YOFF; R2: Xs at 0) ---
        {
            const float* src = R2 ? xim : im;
            float* dst = R2 ? &SU[0] : &SU[YOFF];
            for (int e = t; e < M * YSTR; e += 128) {
                int i = e / YSTR, ch = e - i * YSTR;
                float v = 0.f;
                if (ch < NP) {
                    int p = gix[i];
                    v = src[(p / HP + ch / 7) * IMG_W + (p % HP + ch % 7)];
                }
                dst[i * YSTR + ch] = v;
            }
        }
        __syncthreads();
        // --- Gram, slot-distributed over 128 threads, results in registers ---
        float gsum[NS];
        {
            const float* base = R2 ? &SU[0] : &SU[YOFF];
#pragma unroll
            for (int s = 0; s < NS; ++s) {
                float sum = 0.f;
                if (siR[s] >= 0) {
                    const float* Pi = base + siR[s] * YSTR;
                    const float* Pj = base + sjR[s] * YSTR;
#pragma unroll
                    for (int q = 0; q < 13; ++q) {
                        float4 a = *(const float4*)(Pi + 4 * q);
                        float4 c4 = *(const float4*)(Pj + 4 * q);
                        sum = fmaf(a.x, c4.x, sum);
                        sum = fmaf(a.y, c4.y, sum);
                        sum = fmaf(a.z, c4.z, sum);
                        sum = fmaf(a.w, c4.w, sum);
                    }
                    if (R2 && siR[s] == sjR[s]) sum += cns;
                }
                gsum[s] = sum;
            }
        }
        __syncthreads();  // all Gram reads complete before A overlays Xs region
        // --- write packed A; R2: stage Ys (overwrites dead Xs tail) ---
#pragma unroll
        for (int s = 0; s < NS; ++s)
            if (siR[s] >= 0) SU[RO::f(siR[s]) + sjR[s]] = gsum[s];
        if (R2) {
            for (int e = t; e < M * YSTR; e += 128) {
                int i = e / YSTR, ch = e - i * YSTR;
                float v = 0.f;
                if (ch < NP) {
                    int p = gix[i];
                    v = im[(p / HP + ch / 7) * IMG_W + (p % HP + ch % 7)];
                }
                SU[YOFF + i * YSTR + ch] = v;
            }
        }
        __syncthreads();
        // --- wave0: register-row Cholesky (d^2 form), zero barriers ---
        if (wv == 0) {
            float gr_[PADM];
            if (lane < M) {
#pragma unroll
                for (int j = 0; j < PADM; ++j) {
                    if (j >= M) gr_[j] = 0.f;
                    else gr_[j] = (j <= lane) ? SU[RO::f(lane) + j] : SU[RO::f(j) + lane];
                }
            } else {
#pragma unroll
                for (int j = 0; j < PADM; ++j) gr_[j] = (j == lane) ? 1.f : 0.f;
            }
#pragma unroll
            for (int k = 0; k < PADM - 1; ++k) {
                cbuf[lane] = gr_[k];
                float ivd = 1.f / cbuf[k];
                float fk = gr_[k] * ivd;
#pragma unroll
                for (int jb = (k + 1) / 4; jb < NCH; ++jb) {
                    float4 cv = *(const float4*)&cbuf[4 * jb];
                    if (4 * jb + 0 > k) gr_[4 * jb + 0] = fmaf(-fk, cv.x, gr_[4 * jb + 0]);
                    if (4 * jb + 1 > k) gr_[4 * jb + 1] = fmaf(-fk, cv.y, gr_[4 * jb + 1]);
                    if (4 * jb + 2 > k) gr_[4 * jb + 2] = fmaf(-fk, cv.z, gr_[4 * jb + 2]);
                    if (4 * jb + 3 > k) gr_[4 * jb + 3] = fmaf(-fk, cv.w, gr_[4 * jb + 3]);
                }
            }
            if (lane < PADM) rdiag[lane] = (lane < M) ? 1.f / sqrtf(gr_[lane]) : 1.f;
            if (lane < PADM) {
#pragma unroll
                for (int jb = 0; jb < NCH; ++jb) {
                    if (4 * jb <= lane) {
                        float4 rd4 = *(const float4*)&rdiag[4 * jb];
                        float4 o;
                        o.x = gr_[4 * jb + 0] * rd4.x;
                        o.y = gr_[4 * jb + 1] * rd4.y;
                        o.z = gr_[4 * jb + 2] * rd4.z;
                        o.w = gr_[4 * jb + 3] * rd4.w;
                        *(float4*)&SU[RO::f(lane) + 4 * jb] = o;
                    }
                }
            }
        }
        __syncthreads();
        // --- solves: wave0 lane -> identity col (weights), wave1 lane -> Y col ---
        const bool isId = (wv == 0) && (lane < M);
        const bool isY = (wv == 1) && (lane < NP);
        const int ch = (wv == 1 && lane < NP) ? lane : 0;
        float bb[PADM];
        if (wv == 1) {
#pragma unroll
            for (int i = 0; i < PADM; ++i) bb[i] = (i < M) ? SU[YOFF + i * YSTR + ch] : 0.f;
        } else {
#pragma unroll
            for (int i = 0; i < PADM; ++i) bb[i] = (i == lane) ? 1.f : 0.f;
        }
        // forward: L z = b, 4-wide chunks; all L loads wave-uniform broadcasts
#pragma unroll
        for (int ck = 0; ck < NCH; ++ck) {
            const int i0 = 4 * ck;
            float L10 = SU[RO::f(4 * ck + 1) + 4 * ck];
            float L20 = SU[RO::f(4 * ck + 2) + 4 * ck], L21 = SU[RO::f(4 * ck + 2) + 4 * ck + 1];
            float L30 = SU[RO::f(4 * ck + 3) + 4 * ck], L31 = SU[RO::f(4 * ck + 3) + 4 * ck + 1],
                  L32 = SU[RO::f(4 * ck + 3) + 4 * ck + 2];
            float b0 = bb[i0] * rdiag[i0];
            float b1 = (bb[i0 + 1] - L10 * b0) * rdiag[i0 + 1];
            float b2 = (bb[i0 + 2] - L20 * b0 - L21 * b1) * rdiag[i0 + 2];
            float b3 = (bb[i0 + 3] - L30 * b0 - L31 * b1 - L32 * b2) * rdiag[i0 + 3];
            bb[i0] = b0; bb[i0 + 1] = b1; bb[i0 + 2] = b2; bb[i0 + 3] = b3;
#pragma unroll
            for (int j = 4 * ck + 4; j < PADM; ++j) {
                float4 L4 = *(const float4*)&SU[RO::f(j) + 4 * ck];
                bb[j] = fmaf(-L4.x, b0, fmaf(-L4.y, b1, fmaf(-L4.z, b2, fmaf(-L4.w, b3, bb[j]))));
            }
            if (ck & 1) asm volatile("" ::: "memory");
        }
        // backward: L^T x = z, row sweeps as aligned float4 + compile-time tails
#pragma unroll
        for (int i = PADM - 1; i >= 0; --i) {
            float bbi = bb[i] * rdiag[i];
            bb[i] = bbi;
#pragma unroll
            for (int qb = 0; qb < i / 4; ++qb) {
                float4 L4 = *(const float4*)&SU[RO::f(i) + 4 * qb];
                bb[4 * qb + 0] = fmaf(-L4.x, bbi, bb[4 * qb + 0]);
                bb[4 * qb + 1] = fmaf(-L4.y, bbi, bb[4 * qb + 1]);
                bb[4 * qb + 2] = fmaf(-L4.z, bbi, bb[4 * qb + 2]);
                bb[4 * qb + 3] = fmaf(-L4.w, bbi, bb[4 * qb + 3]);
            }
#pragma unroll
            for (int j = i & ~3; j < i; ++j)
                bb[j] = fmaf(-SU[RO::f(i) + j], bbi, bb[j]);
            if ((i & 7) == 0) asm volatile("" ::: "memory");
        }
        // --- weights (theta symmetric), X_hat write-back ---
        if (isId) {
            float s2 = 0.f;
#pragma unroll
            for (int i = 0; i < M; ++i) {
                float th = ((i == lane) ? 1.f : 0.f) - cns * bb[i];
                s2 = fmaf(th, th, s2);
            }
            s2 = fminf(fmaxf(s2, 1.f / (float)M), 1.f);
            wsh[lane] = 1.f / s2;
        }
        if (isY) {
#pragma unroll
            for (int i = 0; i < M; ++i)
                SU[YOFF + i * YSTR + ch] = fmaf(-cns, bb[i], SU[YOFF + i * YSTR + ch]);
        }
        __syncthreads();
        // --- scatter into LDS pixel region (ds atomics) ---
        for (int e = t; e < M * NP; e += 128) {
            int i = e / NP, c2 = e % NP;
            int p = gix[i];
            int lr = (p / HP + c2 / 7) - row0p;
            int lc = (p % HP + c2 % 7) - col0p;
            float wi = wsh[i];
            atomicAdd(&Nl[lr * PXC + lc], SU[YOFF + i * YSTR + c2] * wi);
            atomicAdd(&Wl[lr * PXC + lc], wi);
        }
    }
    __syncthreads();
    // --- flush region: one global atomic pair per nonzero pixel ---
    float* aA = accPix + (size_t)n * IMG_SZ * 2;
    for (int e = t; e < PXR * PXC; e += 128) {
        float w = Wl[e];
        if (w != 0.f) {
            int gr2 = row0p + e / PXC, gc = col0p + e % PXC;
            if (gr2 < IMG_H && gc < IMG_W) {
                atomicAdd(&aA[(gr2 * IMG_W + gc) * 2], Nl[e]);
                atomicAdd(&aA[(gr2 * IMG_W + gc) * 2 + 1], w);
            }
        }
    }
}

extern "C" void kernel_launch(void* const* d_in, const int* in_sizes, int n_in,
                              void* d_out, int out_size, void* d_ws, size_t ws_size,
                              hipStream_t stream) {
    const float* y = (const float*)d_in[0];
    const float* sigma = (const float*)d_in[1];
    float* out = (float*)d_out;

    char* ws = (char*)d_ws;
    size_t off = 0;
    auto carve = [&](size_t bytes) {
        void* p = ws + off;
        off += (bytes + 255) & ~(size_t)255;
        return p;
    };
    int* idx1 = (int*)carve((size_t)NIMG * NB * 18 * sizeof(int));
    int* idx2 = (int*)carve((size_t)NIMG * NB * 55 * sizeof(int));
    float* accPix = (float*)carve((size_t)NIMG * IMG_SZ * 2 * sizeof(float));
    float* den1 = (float*)carve((size_t)NIMG * IMG_SZ * sizeof(float));

    const int accTotal = NIMG * IMG_SZ * 2;
    const int imgTotal = NIMG * IMG_SZ;

    // Round 1: M1=18
    zero_kernel<<<(accTotal + 255) / 256, 256, 0, stream>>>(accPix, accTotal);
    bm_kernel<18><<<dim3(16, 64, NIMG), 256, 0, stream>>>(y, idx1);
    denoise_kernel<18, false><<<dim3(16, 64, NIMG), 128, 0, stream>>>(y, y, idx1, sigma, accPix);
    div_kernel<<<(imgTotal + 255) / 256, 256, 0, stream>>>(accPix, den1, imgTotal);

    // Round 2: M2=55
    zero_kernel<<<(accTotal + 255) / 256, 256, 0, stream>>>(accPix, accTotal);
    bm_kernel<55><<<dim3(16, 64, NIMG), 256, 0, stream>>>(den1, idx2);
    denoise_kernel<55, true><<<dim3(16, 64, NIMG), 128, 0, stream>>>(y, den1, idx2, sigma, accPix);
    div_kernel<<<(imgTotal + 255) / 256, 256, 0, stream>>>(accPix, out, imgTotal);
}

// Round 13
// 940.032 us; speedup vs baseline: 1.6643x; 1.6643x over previous
//
#include <hip/hip_runtime.h>
#include <math.h>

#define IMG_H 256
#define IMG_W 256
#define IMG_SZ (IMG_H * IMG_W)
#define NP 49      /* C*p*p patch vector length */
#define HP 250     /* H - p + 1 */
#define NPAT 62500 /* HP*HP patches per image */
#define NB 4096    /* groups per image = 64*64 */
#define NCAND 1369 /* 37*37 */
#define VRAD 18
#define CENTER (VRAD * 37 + VRAD)
#define NIMG 2
#define YSTR 52    /* patch row stride: 208B, 16B aligned */
#define WSTR 55    /* bm window stride: odd -> conflict-free */

// Map aligned-patch coordinates (253x253, after align_corners with s=4 on a
// 250x250 grid) to original patch coordinates. Returns false for inf slots.
__device__ __forceinline__ bool align_map(int r, int c, int& ro, int& co) {
    if (r < 0 || r > 252 || c < 0 || c > 252) return false;
    if (r == 252) {
        if (c == 252) { ro = 249; co = 249; return true; }
        if (c <= 248 && (c & 3) == 0) { ro = 249; co = c; return true; }
        return false;
    }
    if (c == 252) {
        if (r <= 248 && (r & 3) == 0) { ro = r; co = 249; return true; }
        return false;
    }
    if (r >= 250 || c >= 250) return false;
    if (r == 249) {
        if (c == 249) return false;
        if ((c & 3) == 0) return false;
        ro = 249; co = c; return true;
    }
    if (c == 249) {
        if ((r & 3) == 0) return false;
        ro = r; co = 249; return true;
    }
    ro = r; co = c; return true;
}

__global__ void zero_kernel(float* __restrict__ p, int total) {
    int i = blockIdx.x * blockDim.x + threadIdx.x;
    if (i < total) p[i] = 0.0f;
}

// PIXEL-mode: acc holds interleaved (num, weight) pairs per pixel.
__global__ void div_kernel(const float* __restrict__ acc, float* __restrict__ out, int total) {
    int i = blockIdx.x * blockDim.x + threadIdx.x;
    if (i < total) out[i] = acc[2 * i] / acc[2 * i + 1];
}

// PATCH-mode fold: one block per 8x8 pixel tile. Stage the 14x14 covering
// patch rows into LDS (coalesced), then 4 threads/pixel split the 7 ki rows
// and quad-reduce.
__global__ __launch_bounds__(256) void fold_div_kernel(const float* __restrict__ Xacc,
                                                       const float* __restrict__ Wacc,
                                                       float* __restrict__ out) {
    __shared__ __align__(16) float Xs[196 * 49];
    __shared__ float Ws[196];
    const int tc = blockIdx.x, tr = blockIdx.y, n = blockIdx.z;
    const int r0 = tr * 8, c0 = tc * 8;
    const int pr0 = r0 - 6, pc0 = c0 - 6;
    const int t = threadIdx.x;
    const float* Xn = Xacc + (size_t)n * NPAT * NP;
    const float* Wn = Wacc + (size_t)n * NPAT;
    for (int e = t; e < 196 * 49; e += 256) {
        int pr_l = e / 686, rem = e - pr_l * 686;
        int pc_l = rem / 49, ch = rem - pc_l * 49;
        int pr = pr0 + pr_l, pc = pc0 + pc_l;
        float v = 0.f;
        if (pr >= 0 && pr < HP && pc >= 0 && pc < HP)
            v = Xn[(size_t)(pr * HP + pc) * NP + ch];
        Xs[e] = v;
    }
    for (int e = t; e < 196; e += 256) {
        int pr = pr0 + e / 14, pc = pc0 + e % 14;
        float v = 0.f;
        if (pr >= 0 && pr < HP && pc >= 0 && pc < HP) v = Wn[pr * HP + pc];
        Ws[e] = v;
    }
    __syncthreads();
    const int p = t >> 2, part = t & 3;
    const int prx = p >> 3, pcx = p & 7;  // pixel within tile
    float num = 0.f, den = 0.f;
    const int ki0 = part * 2;
    const int kiN = (part == 3) ? 1 : 2;
    for (int kk = 0; kk < kiN; ++kk) {
        int ki = ki0 + kk;
        int pr_l = prx + 6 - ki;
#pragma unroll
        for (int kj = 0; kj < 7; ++kj) {
            int pc_l = pcx + 6 - kj;
            num += Xs[pr_l * 686 + pc_l * 49 + ki * 7 + kj];
            den += Ws[pr_l * 14 + pc_l];
        }
    }
    num += __shfl_xor(num, 1);
    den += __shfl_xor(den, 1);
    num += __shfl_xor(num, 2);
    den += __shfl_xor(den, 2);
    if (part == 0)
        out[(size_t)n * IMG_SZ + (r0 + prx) * IMG_W + (c0 + pcx)] = num / den;
}

// 4 reference patches per 256-thread block (one wave each), sharing one staged
// union window. refp in registers; center forced during fill; selection via
// barrier-free shfl butterfly over per-lane top-2 caches.
template <int M>
__global__ __launch_bounds__(256) void bm_kernel(const float* __restrict__ img,
                                                 int* __restrict__ idx_out) {
    __shared__ float win[43 * WSTR];
    __shared__ float dist[4][NCAND];
    const int llb = blockIdx.x, kk = blockIdx.y, n = blockIdx.z;
    const float* im = img + (size_t)n * IMG_SZ;
    const int t = threadIdx.x;
    const int w = t >> 6, lane = t & 63;
    const int ll = 4 * llb + w;
    const int rr = (kk < 63) ? 4 * kk : 249;
    const int cc = (ll < 63) ? 4 * ll : 249;
    const int ar0 = 4 * kk, ac0 = 4 * ll;
    const int acb = 16 * llb;
    const int row0 = max(0, ar0 - VRAD), col0 = max(0, acb - VRAD);
    const int row1 = min(IMG_H - 1, ar0 + VRAD + 6);
    const int col1 = min(IMG_W - 1, acb + 12 + VRAD + 6);
    const int nr = row1 - row0 + 1, nc = col1 - col0 + 1;
    for (int e = t; e < nr * nc; e += 256) {
        int r = e / nc, c = e % nc;
        win[r * WSTR + c] = im[(row0 + r) * IMG_W + col0 + c];
    }
    __syncthreads();
    float rf[NP];
    {
        const float* rb = &win[(rr - row0) * WSTR + (cc - col0)];
#pragma unroll
        for (int ki = 0; ki < 7; ++ki)
#pragma unroll
            for (int kj = 0; kj < 7; ++kj) rf[ki * 7 + kj] = rb[ki * WSTR + kj];
    }
    float* dw = dist[w];
    for (int cand = lane; cand < NCAND; cand += 64) {
        const int dr = cand / 37 - VRAD, dc = cand % 37 - VRAD;
        int ro, co;
        float d;
        if (align_map(ar0 + dr, ac0 + dc, ro, co)) {
            const float* base = &win[(ro - row0) * WSTR + (co - col0)];
            float s = 0.f;
#pragma unroll
            for (int ki = 0; ki < 7; ++ki)
#pragma unroll
                for (int kj = 0; kj < 7; ++kj) {
                    float df = base[ki * WSTR + kj] - rf[ki * 7 + kj] + 1e-6f;
                    s = fmaf(df, df, s);
                }
            d = sqrtf(s);
        } else {
            d = INFINITY;
        }
        if (cand == CENTER) d = -1.0f;  // center always wins sel 0
        dw[cand] = d;
    }
    __syncthreads();
    // per-lane top-2 over the strided bucket (ascending scan => ties keep low idx)
    float v1 = INFINITY, v2 = INFINITY;
    int i1 = NCAND, i2 = NCAND;
    for (int c = lane; c < NCAND; c += 64) {
        float v = dw[c];
        if (v < v1) { v2 = v1; i2 = i1; v1 = v; i1 = c; }
        else if (v < v2) { v2 = v; i2 = c; }
    }
    int* out = idx_out + (size_t)((n * 64 + kk) * 64 + ll) * M;
    for (int sel = 0; sel < M; ++sel) {
        float gv = v1;
        int gi = i1;
#pragma unroll
        for (int off = 32; off; off >>= 1) {
            float vv = __shfl_xor(gv, off);
            int ii = __shfl_xor(gi, off);
            if (vv < gv || (vv == gv && ii < gi)) { gv = vv; gi = ii; }
        }
        if (lane == 0) {
            int dr = gi / 37 - VRAD, dc = gi % 37 - VRAD;
            out[sel] = min(rr + dr, 249) * HP + min(cc + dc, 249);
        }
        if ((gi & 63) == lane) {  // owner pops its cache; rescan only if exhausted
            dw[gi] = INFINITY;
            v1 = v2; i1 = i2; v2 = INFINITY; i2 = NCAND;
            if (i1 == NCAND) {
                for (int c = lane; c < NCAND; c += 64) {
                    float v = dw[c];
                    if (v < v1) { v2 = v1; i2 = i1; v1 = v; i1 = c; }
                    else if (v < v2) { v2 = v; i2 = c; }
                }
            }
        }
    }
}

// 128 threads (2 waves) per group. theta = I - c*A^-1 in BOTH rounds.
// LDS union SU = [packed-L | patch rows] (padded to PADM rows so tiled-Gram
// over-reads stay in-array). Gram: 2-D register tiling — each thread computes
// a 4x4 tile of G, reading 8 rows instead of one row-pair per entry (3.7x
// less LDS traffic than slot-per-entry); results held in registers across the
// barrier, written guarded to the packed lower triangle. Cholesky: wave0-only
// register rows (d^2 form, row reconstructed from packed symmetry), zero
// barriers. Solve: wave0 = M identity cols (weights), wave1 = 49 Y cols
// (X_hat); uniform broadcast float4 L reads at constexpr packed offsets.
// Epilogue: per-PATCH atomics (AGGP) or per-pixel fallback.
template <int M, bool R2, bool AGGP>
__global__ __launch_bounds__(128, 2) void denoise_kernel(
    const float* __restrict__ y, const float* __restrict__ xsrc,
    const int* __restrict__ idx, const float* __restrict__ sigma_p,
    float* __restrict__ accPix, float* __restrict__ Xacc, float* __restrict__ Wacc) {
    constexpr int PADM = (M + 3) & ~3;  // 56 for M=55, 20 for M=18
    constexpr int NCH = PADM / 4;
    constexpr int TR = PADM / 4;            // Gram tile-rows
    constexpr int NT = TR * (TR + 1) / 2;   // 105 / 15 tiles
    // packed row offset (floats), each row 16B aligned: sum_{k<i} roundup4(k+1)
    struct RO { static constexpr int f(int i) {
        int a = i >> 2, b = i & 3; return 8 * a * (a + 1) + 4 * (a + 1) * b; } };
    constexpr int LSZ = RO::f(PADM);
    constexpr int YOFF = LSZ;               // patch rows live after the packed L
    constexpr int UN = LSZ + PADM * YSTR;   // padded: tile reads up to row PADM-1
    __shared__ __align__(16) float SU[UN];
    __shared__ float cbuf[64];
    __shared__ __align__(16) float rdiag[PADM];
    __shared__ float wsh[M];
    __shared__ int gix[M];
    const int b = blockIdx.x, n = blockIdx.y;
    const int t = threadIdx.x;
    const int lane = t & 63, wv = t >> 6;
    if (t < M) gix[t] = idx[(size_t)(n * NB + b) * M + t];
    __syncthreads();
    const float* im = y + (size_t)n * IMG_SZ;
    const float* xim = xsrc + (size_t)n * IMG_SZ;
    // --- stage Gram source rows (R1: Ys at YOFF; R2: Xs at 0) ---
    {
        const float* src = R2 ? xim : im;
        float* dst = R2 ? &SU[0] : &SU[YOFF];
        for (int e = t; e < M * YSTR; e += 128) {
            int i = e / YSTR, ch = e - i * YSTR;
            float v = 0.f;
            if (ch < NP) {
                int p = gix[i];
                v = src[(p / HP + ch / 7) * IMG_W + (p % HP + ch % 7)];
            }
            dst[i * YSTR + ch] = v;
        }
    }
    __syncthreads();
    const float sg = sigma_p[0];
    const float cns = 49.f * sg * sg;
    // --- tiled Gram: thread t -> 4x4 tile (ti,tj), tj<=ti; acc in registers.
    // Rows >= M read garbage (in-array pad); those entries never written.
    float acc[4][4];
    int ti = 0, tj = 0;
    const bool gact = (t < NT);
    if (gact) {
        ti = (int)((sqrtf(8.f * t + 1.f) - 1.f) * 0.5f);
        while ((ti + 1) * (ti + 2) / 2 <= t) ++ti;
        while (ti * (ti + 1) / 2 > t) --ti;
        tj = t - ti * (ti + 1) / 2;
        const float* base = R2 ? &SU[0] : &SU[YOFF];
        const float* Ar = base + 4 * ti * YSTR;
        const float* Br = base + 4 * tj * YSTR;
#pragma unroll
        for (int r = 0; r < 4; ++r)
#pragma unroll
            for (int s = 0; s < 4; ++s) acc[r][s] = 0.f;
#pragma unroll
        for (int q = 0; q < 13; ++q) {
            float4 av[4], bv[4];
#pragma unroll
            for (int r = 0; r < 4; ++r) av[r] = *(const float4*)(Ar + r * YSTR + 4 * q);
#pragma unroll
            for (int s = 0; s < 4; ++s) bv[s] = *(const float4*)(Br + s * YSTR + 4 * q);
#pragma unroll
            for (int r = 0; r < 4; ++r)
#pragma unroll
                for (int s = 0; s < 4; ++s) {
                    acc[r][s] = fmaf(av[r].x, bv[s].x, acc[r][s]);
                    acc[r][s] = fmaf(av[r].y, bv[s].y, acc[r][s]);
                    acc[r][s] = fmaf(av[r].z, bv[s].z, acc[r][s]);
                    acc[r][s] = fmaf(av[r].w, bv[s].w, acc[r][s]);
                }
        }
    }
    __syncthreads();  // all Gram reads complete before A overlays Xs region
    // --- write packed A (guarded); R2: stage Ys (overwrites dead Xs tail) ---
    if (gact) {
#pragma unroll
        for (int r = 0; r < 4; ++r)
#pragma unroll
            for (int s = 0; s < 4; ++s) {
                int gi2 = 4 * ti + r, gj2 = 4 * tj + s;
                if (gj2 <= gi2 && gi2 < M) {
                    float v = acc[r][s];
                    if (R2 && gi2 == gj2) v += cns;
                    SU[RO::f(gi2) + gj2] = v;
                }
            }
    }
    if (R2) {
        for (int e = t; e < M * YSTR; e += 128) {
            int i = e / YSTR, ch = e - i * YSTR;
            float v = 0.f;
            if (ch < NP) {
                int p = gix[i];
                v = im[(p / HP + ch / 7) * IMG_W + (p % HP + ch % 7)];
            }
            SU[YOFF + i * YSTR + ch] = v;
        }
    }
    __syncthreads();
    // --- wave0: register-row Cholesky (d^2 form), zero barriers ---
    if (wv == 0) {
        float g[PADM];
        if (lane < M) {
#pragma unroll
            for (int j = 0; j < PADM; ++j) {
                if (j >= M) g[j] = 0.f;
                else g[j] = (j <= lane) ? SU[RO::f(lane) + j] : SU[RO::f(j) + lane];
            }
        } else {
#pragma unroll
            for (int j = 0; j < PADM; ++j) g[j] = (j == lane) ? 1.f : 0.f;
        }
#pragma unroll
        for (int k = 0; k < PADM - 1; ++k) {
            cbuf[lane] = g[k];
            float ivd = 1.f / cbuf[k];
            float fk = g[k] * ivd;
#pragma unroll
            for (int jb = (k + 1) / 4; jb < NCH; ++jb) {
                float4 cv = *(const float4*)&cbuf[4 * jb];
                if (4 * jb + 0 > k) g[4 * jb + 0] = fmaf(-fk, cv.x, g[4 * jb + 0]);
                if (4 * jb + 1 > k) g[4 * jb + 1] = fmaf(-fk, cv.y, g[4 * jb + 1]);
                if (4 * jb + 2 > k) g[4 * jb + 2] = fmaf(-fk, cv.z, g[4 * jb + 2]);
                if (4 * jb + 3 > k) g[4 * jb + 3] = fmaf(-fk, cv.w, g[4 * jb + 3]);
            }
        }
        if (lane < PADM) rdiag[lane] = (lane < M) ? 1.f / sqrtf(g[lane]) : 1.f;
        // scale row by rdiag[col], store packed L (only j<=i read by solves)
        if (lane < PADM) {
#pragma unroll
            for (int jb = 0; jb < NCH; ++jb) {
                if (4 * jb <= lane) {
                    float4 rd4 = *(const float4*)&rdiag[4 * jb];
                    float4 o;
                    o.x = g[4 * jb + 0] * rd4.x;
                    o.y = g[4 * jb + 1] * rd4.y;
                    o.z = g[4 * jb + 2] * rd4.z;
                    o.w = g[4 * jb + 3] * rd4.w;
                    *(float4*)&SU[RO::f(lane) + 4 * jb] = o;
                }
            }
        }
    }
    __syncthreads();
    // --- solves: wave0 lane -> identity col (weights), wave1 lane -> Y col ---
    const bool isId = (wv == 0) && (lane < M);
    const bool isY = (wv == 1) && (lane < NP);
    const int ch = (wv == 1 && lane < NP) ? lane : 0;
    float bb[PADM];
    if (wv == 1) {
#pragma unroll
        for (int i = 0; i < PADM; ++i) bb[i] = (i < M) ? SU[YOFF + i * YSTR + ch] : 0.f;
    } else {
#pragma unroll
        for (int i = 0; i < PADM; ++i) bb[i] = (i == lane) ? 1.f : 0.f;
    }
    // forward: L z = b, 4-wide chunks; all L loads wave-uniform broadcasts
#pragma unroll
    for (int ck = 0; ck < NCH; ++ck) {
        const int i0 = 4 * ck;
        float L10 = SU[RO::f(4 * ck + 1) + 4 * ck];
        float L20 = SU[RO::f(4 * ck + 2) + 4 * ck], L21 = SU[RO::f(4 * ck + 2) + 4 * ck + 1];
        float L30 = SU[RO::f(4 * ck + 3) + 4 * ck], L31 = SU[RO::f(4 * ck + 3) + 4 * ck + 1],
              L32 = SU[RO::f(4 * ck + 3) + 4 * ck + 2];
        float b0 = bb[i0] * rdiag[i0];
        float b1 = (bb[i0 + 1] - L10 * b0) * rdiag[i0 + 1];
        float b2 = (bb[i0 + 2] - L20 * b0 - L21 * b1) * rdiag[i0 + 2];
        float b3 = (bb[i0 + 3] - L30 * b0 - L31 * b1 - L32 * b2) * rdiag[i0 + 3];
        bb[i0] = b0; bb[i0 + 1] = b1; bb[i0 + 2] = b2; bb[i0 + 3] = b3;
#pragma unroll
        for (int j = 4 * ck + 4; j < PADM; ++j) {
            float4 L4 = *(const float4*)&SU[RO::f(j) + 4 * ck];
            bb[j] = fmaf(-L4.x, b0, fmaf(-L4.y, b1, fmaf(-L4.z, b2, fmaf(-L4.w, b3, bb[j]))));
        }
        if (ck & 1) asm volatile("" ::: "memory");  // 2-chunk load-hoist window
    }
    // backward: L^T x = z, row sweeps as aligned float4 + compile-time tails
#pragma unroll
    for (int i = PADM - 1; i >= 0; --i) {
        float bbi = bb[i] * rdiag[i];
        bb[i] = bbi;
#pragma unroll
        for (int qb = 0; qb < i / 4; ++qb) {
            float4 L4 = *(const float4*)&SU[RO::f(i) + 4 * qb];
            bb[4 * qb + 0] = fmaf(-L4.x, bbi, bb[4 * qb + 0]);
            bb[4 * qb + 1] = fmaf(-L4.y, bbi, bb[4 * qb + 1]);
            bb[4 * qb + 2] = fmaf(-L4.z, bbi, bb[4 * qb + 2]);
            bb[4 * qb + 3] = fmaf(-L4.w, bbi, bb[4 * qb + 3]);
        }
#pragma unroll
        for (int j = i & ~3; j < i; ++j)
            bb[j] = fmaf(-SU[RO::f(i) + j], bbi, bb[j]);
        if ((i & 7) == 0) asm volatile("" ::: "memory");  // 8-row hoist window
    }
    // --- weights (theta symmetric via identity columns) ---
    float wloc = 0.f;
    if (isId) {
        float s2 = 0.f;
#pragma unroll
        for (int i = 0; i < M; ++i) {
            float th = ((i == lane) ? 1.f : 0.f) - cns * bb[i];
            s2 = fmaf(th, th, s2);
        }
        s2 = fminf(fmaxf(s2, 1.f / (float)M), 1.f);
        wloc = 1.f / s2;
        wsh[lane] = wloc;
    }
    if (!AGGP && isY) {
#pragma unroll
        for (int i = 0; i < M; ++i)
            SU[YOFF + i * YSTR + ch] = fmaf(-cns, bb[i], SU[YOFF + i * YSTR + ch]);
    }
    __syncthreads();
    if (AGGP) {
        // per-PATCH scatter: ~7-way contention, lane-coalesced Xacc lines
        if (isId) atomicAdd(&Wacc[(size_t)n * NPAT + gix[lane]], wloc);
        if (isY) {
#pragma unroll
            for (int i = 0; i < M; ++i) {
                float xv = fmaf(-cns, bb[i], SU[YOFF + i * YSTR + ch]);
                atomicAdd(&Xacc[((size_t)n * NPAT + gix[i]) * NP + ch], xv * wsh[i]);
            }
        }
    } else {
        float* aA = accPix + (size_t)n * IMG_SZ * 2;
        for (int e = t; e < M * NP; e += 128) {
            int i = e / NP, c2 = e % NP;
            int p = gix[i];
            int pix = (p / HP + c2 / 7) * IMG_W + (p % HP + c2 % 7);
            float wi = wsh[i];
            atomicAdd(&aA[pix * 2], SU[YOFF + i * YSTR + c2] * wi);
            atomicAdd(&aA[pix * 2 + 1], wi);
        }
    }
}

extern "C" void kernel_launch(void* const* d_in, const int* in_sizes, int n_in,
                              void* d_out, int out_size, void* d_ws, size_t ws_size,
                              hipStream_t stream) {
    const float* y = (const float*)d_in[0];
    const float* sigma = (const float*)d_in[1];
    float* out = (float*)d_out;

    char* ws = (char*)d_ws;
    size_t off = 0;
    auto carve = [&](size_t bytes) {
        void* p = ws + off;
        off += (bytes + 255) & ~(size_t)255;
        return p;
    };
    int* idx1 = (int*)carve((size_t)NIMG * NB * 18 * sizeof(int));
    int* idx2 = (int*)carve((size_t)NIMG * NB * 55 * sizeof(int));
    float* accPix = (float*)carve((size_t)NIMG * IMG_SZ * 2 * sizeof(float));
    float* den1 = (float*)carve((size_t)NIMG * IMG_SZ * sizeof(float));
    // PATCH-mode accumulators: X then W contiguous (zeroed together)
    const size_t xw_floats = (size_t)NIMG * NPAT * (NP + 1);
    float* Xacc = (float*)carve(xw_floats * sizeof(float));
    float* Wacc = Xacc + (size_t)NIMG * NPAT * NP;
    const bool patchMode = (off <= ws_size);

    const int imgTotal = NIMG * IMG_SZ;

    if (patchMode) {
        const int xwTotal = (int)xw_floats;
        // Round 1: M1=18
        zero_kernel<<<(xwTotal + 255) / 256, 256, 0, stream>>>(Xacc, xwTotal);
        bm_kernel<18><<<dim3(16, 64, NIMG), 256, 0, stream>>>(y, idx1);
        denoise_kernel<18, false, true><<<dim3(NB, NIMG), 128, 0, stream>>>(
            y, y, idx1, sigma, accPix, Xacc, Wacc);
        fold_div_kernel<<<dim3(32, 32, NIMG), 256, 0, stream>>>(Xacc, Wacc, den1);
        // Round 2: M2=55
        zero_kernel<<<(xwTotal + 255) / 256, 256, 0, stream>>>(Xacc, xwTotal);
        bm_kernel<55><<<dim3(16, 64, NIMG), 256, 0, stream>>>(den1, idx2);
        denoise_kernel<55, true, true><<<dim3(NB, NIMG), 128, 0, stream>>>(
            y, den1, idx2, sigma, accPix, Xacc, Wacc);
        fold_div_kernel<<<dim3(32, 32, NIMG), 256, 0, stream>>>(Xacc, Wacc, out);
    } else {
        const int accTotal = NIMG * IMG_SZ * 2;
        // Round 1: M1=18
        zero_kernel<<<(accTotal + 255) / 256, 256, 0, stream>>>(accPix, accTotal);
        bm_kernel<18><<<dim3(16, 64, NIMG), 256, 0, stream>>>(y, idx1);
        denoise_kernel<18, false, false><<<dim3(NB, NIMG), 128, 0, stream>>>(
            y, y, idx1, sigma, accPix, Xacc, Wacc);
        div_kernel<<<(imgTotal + 255) / 256, 256, 0, stream>>>(accPix, den1, imgTotal);
        // Round 2: M2=55
        zero_kernel<<<(accTotal + 255) / 256, 256, 0, stream>>>(accPix, accTotal);
        bm_kernel<55><<<dim3(16, 64, NIMG), 256, 0, stream>>>(den1, idx2);
        denoise_kernel<55, true, false><<<dim3(NB, NIMG), 128, 0, stream>>>(
            y, den1, idx2, sigma, accPix, Xacc, Wacc);
        div_kernel<<<(imgTotal + 255) / 256, 256, 0, stream>>>(accPix, out, imgTotal);
    }
}

// Round 14
// 922.954 us; speedup vs baseline: 1.6951x; 1.0185x over previous
//
#include <hip/hip_runtime.h>
#include <math.h>

#define IMG_H 256
#define IMG_W 256
#define IMG_SZ (IMG_H * IMG_W)
#define NP 49      /* C*p*p patch vector length */
#define HP 250     /* H - p + 1 */
#define NPAT 62500 /* HP*HP patches per image */
#define NB 4096    /* groups per image = 64*64 */
#define NCAND 1369 /* 37*37 */
#define VRAD 18
#define CENTER (VRAD * 37 + VRAD)
#define NIMG 2
#define YSTR 52    /* patch row stride: 208B, 16B aligned */
#define WSTR 55    /* bm window stride: odd -> conflict-free */

// Map aligned-patch coordinates (253x253, after align_corners with s=4 on a
// 250x250 grid) to original patch coordinates. Returns false for inf slots.
__device__ __forceinline__ bool align_map(int r, int c, int& ro, int& co) {
    if (r < 0 || r > 252 || c < 0 || c > 252) return false;
    if (r == 252) {
        if (c == 252) { ro = 249; co = 249; return true; }
        if (c <= 248 && (c & 3) == 0) { ro = 249; co = c; return true; }
        return false;
    }
    if (c == 252) {
        if (r <= 248 && (r & 3) == 0) { ro = r; co = 249; return true; }
        return false;
    }
    if (r >= 250 || c >= 250) return false;
    if (r == 249) {
        if (c == 249) return false;
        if ((c & 3) == 0) return false;
        ro = 249; co = c; return true;
    }
    if (c == 249) {
        if ((r & 3) == 0) return false;
        ro = r; co = 249; return true;
    }
    ro = r; co = c; return true;
}

__global__ void zero_kernel(float* __restrict__ p, int total) {
    int i = blockIdx.x * blockDim.x + threadIdx.x;
    if (i < total) p[i] = 0.0f;
}

// PIXEL-mode: acc holds interleaved (num, weight) pairs per pixel.
__global__ void div_kernel(const float* __restrict__ acc, float* __restrict__ out, int total) {
    int i = blockIdx.x * blockDim.x + threadIdx.x;
    if (i < total) out[i] = acc[2 * i] / acc[2 * i + 1];
}

// PATCH-mode fold: one block per 8x8 pixel tile. Stage the 14x14 covering
// patch rows into LDS (coalesced), then 4 threads/pixel split the 7 ki rows
// and quad-reduce.
__global__ __launch_bounds__(256) void fold_div_kernel(const float* __restrict__ Xacc,
                                                       const float* __restrict__ Wacc,
                                                       float* __restrict__ out) {
    __shared__ __align__(16) float Xs[196 * 49];
    __shared__ float Ws[196];
    const int tc = blockIdx.x, tr = blockIdx.y, n = blockIdx.z;
    const int r0 = tr * 8, c0 = tc * 8;
    const int pr0 = r0 - 6, pc0 = c0 - 6;
    const int t = threadIdx.x;
    const float* Xn = Xacc + (size_t)n * NPAT * NP;
    const float* Wn = Wacc + (size_t)n * NPAT;
    for (int e = t; e < 196 * 49; e += 256) {
        int pr_l = e / 686, rem = e - pr_l * 686;
        int pc_l = rem / 49, ch = rem - pc_l * 49;
        int pr = pr0 + pr_l, pc = pc0 + pc_l;
        float v = 0.f;
        if (pr >= 0 && pr < HP && pc >= 0 && pc < HP)
            v = Xn[(size_t)(pr * HP + pc) * NP + ch];
        Xs[e] = v;
    }
    for (int e = t; e < 196; e += 256) {
        int pr = pr0 + e / 14, pc = pc0 + e % 14;
        float v = 0.f;
        if (pr >= 0 && pr < HP && pc >= 0 && pc < HP) v = Wn[pr * HP + pc];
        Ws[e] = v;
    }
    __syncthreads();
    const int p = t >> 2, part = t & 3;
    const int prx = p >> 3, pcx = p & 7;  // pixel within tile
    float num = 0.f, den = 0.f;
    const int ki0 = part * 2;
    const int kiN = (part == 3) ? 1 : 2;
    for (int kk = 0; kk < kiN; ++kk) {
        int ki = ki0 + kk;
        int pr_l = prx + 6 - ki;
#pragma unroll
        for (int kj = 0; kj < 7; ++kj) {
            int pc_l = pcx + 6 - kj;
            num += Xs[pr_l * 686 + pc_l * 49 + ki * 7 + kj];
            den += Ws[pr_l * 14 + pc_l];
        }
    }
    num += __shfl_xor(num, 1);
    den += __shfl_xor(den, 1);
    num += __shfl_xor(num, 2);
    den += __shfl_xor(den, 2);
    if (part == 0)
        out[(size_t)n * IMG_SZ + (r0 + prx) * IMG_W + (c0 + pcx)] = num / den;
}

// 4 reference patches per 256-thread block (one wave each), sharing one staged
// union window. refp in registers; center forced during fill; selection via
// barrier-free shfl butterfly over per-lane top-2 caches.
template <int M>
__global__ __launch_bounds__(256) void bm_kernel(const float* __restrict__ img,
                                                 int* __restrict__ idx_out) {
    __shared__ float win[43 * WSTR];
    __shared__ float dist[4][NCAND];
    const int llb = blockIdx.x, kk = blockIdx.y, n = blockIdx.z;
    const float* im = img + (size_t)n * IMG_SZ;
    const int t = threadIdx.x;
    const int w = t >> 6, lane = t & 63;
    const int ll = 4 * llb + w;
    const int rr = (kk < 63) ? 4 * kk : 249;
    const int cc = (ll < 63) ? 4 * ll : 249;
    const int ar0 = 4 * kk, ac0 = 4 * ll;
    const int acb = 16 * llb;
    const int row0 = max(0, ar0 - VRAD), col0 = max(0, acb - VRAD);
    const int row1 = min(IMG_H - 1, ar0 + VRAD + 6);
    const int col1 = min(IMG_W - 1, acb + 12 + VRAD + 6);
    const int nr = row1 - row0 + 1, nc = col1 - col0 + 1;
    for (int e = t; e < nr * nc; e += 256) {
        int r = e / nc, c = e % nc;
        win[r * WSTR + c] = im[(row0 + r) * IMG_W + col0 + c];
    }
    __syncthreads();
    float rf[NP];
    {
        const float* rb = &win[(rr - row0) * WSTR + (cc - col0)];
#pragma unroll
        for (int ki = 0; ki < 7; ++ki)
#pragma unroll
            for (int kj = 0; kj < 7; ++kj) rf[ki * 7 + kj] = rb[ki * WSTR + kj];
    }
    float* dw = dist[w];
    for (int cand = lane; cand < NCAND; cand += 64) {
        const int dr = cand / 37 - VRAD, dc = cand % 37 - VRAD;
        int ro, co;
        float d;
        if (align_map(ar0 + dr, ac0 + dc, ro, co)) {
            const float* base = &win[(ro - row0) * WSTR + (co - col0)];
            float s = 0.f;
#pragma unroll
            for (int ki = 0; ki < 7; ++ki)
#pragma unroll
                for (int kj = 0; kj < 7; ++kj) {
                    float df = base[ki * WSTR + kj] - rf[ki * 7 + kj] + 1e-6f;
                    s = fmaf(df, df, s);
                }
            d = sqrtf(s);
        } else {
            d = INFINITY;
        }
        if (cand == CENTER) d = -1.0f;  // center always wins sel 0
        dw[cand] = d;
    }
    __syncthreads();
    // per-lane top-2 over the strided bucket (ascending scan => ties keep low idx)
    float v1 = INFINITY, v2 = INFINITY;
    int i1 = NCAND, i2 = NCAND;
    for (int c = lane; c < NCAND; c += 64) {
        float v = dw[c];
        if (v < v1) { v2 = v1; i2 = i1; v1 = v; i1 = c; }
        else if (v < v2) { v2 = v; i2 = c; }
    }
    int* out = idx_out + (size_t)((n * 64 + kk) * 64 + ll) * M;
    for (int sel = 0; sel < M; ++sel) {
        float gv = v1;
        int gi = i1;
#pragma unroll
        for (int off = 32; off; off >>= 1) {
            float vv = __shfl_xor(gv, off);
            int ii = __shfl_xor(gi, off);
            if (vv < gv || (vv == gv && ii < gi)) { gv = vv; gi = ii; }
        }
        if (lane == 0) {
            int dr = gi / 37 - VRAD, dc = gi % 37 - VRAD;
            out[sel] = min(rr + dr, 249) * HP + min(cc + dc, 249);
        }
        if ((gi & 63) == lane) {  // owner pops its cache; rescan only if exhausted
            dw[gi] = INFINITY;
            v1 = v2; i1 = i2; v2 = INFINITY; i2 = NCAND;
            if (i1 == NCAND) {
                for (int c = lane; c < NCAND; c += 64) {
                    float v = dw[c];
                    if (v < v1) { v2 = v1; i2 = i1; v1 = v; i1 = c; }
                    else if (v < v2) { v2 = v; i2 = c; }
                }
            }
        }
    }
}

// 128 threads (2 waves) per group. theta = I - c*A^-1 in BOTH rounds.
// LDS union SU = [packed-L | patch rows] (padded rows for tiled-Gram
// over-reads). Gram: 2-D register tiling (4x4 tile per thread). Cholesky:
// wave0-only register rows (d^2 form) with PING-PONG EARLY-COLUMN PUBLISH —
// step k updates g[k+1] first and immediately writes it to the alternate
// column buffer, hiding the LDS read-after-write round-trip under the
// remaining rank-1 updates. Wave1 prefetches its solve RHS concurrently.
// Solve: wave0 = M identity cols (weights), wave1 = 49 Y cols (X_hat);
// uniform broadcast float4 L reads; hoist fences relaxed to 4-chunk/16-row
// windows. Epilogue: per-PATCH atomics (AGGP) or per-pixel fallback.
template <int M, bool R2, bool AGGP>
__global__ __launch_bounds__(128, 2) void denoise_kernel(
    const float* __restrict__ y, const float* __restrict__ xsrc,
    const int* __restrict__ idx, const float* __restrict__ sigma_p,
    float* __restrict__ accPix, float* __restrict__ Xacc, float* __restrict__ Wacc) {
    constexpr int PADM = (M + 3) & ~3;  // 56 for M=55, 20 for M=18
    constexpr int NCH = PADM / 4;
    constexpr int TR = PADM / 4;            // Gram tile-rows
    constexpr int NT = TR * (TR + 1) / 2;   // 105 / 15 tiles
    // packed row offset (floats), each row 16B aligned: sum_{k<i} roundup4(k+1)
    struct RO { static constexpr int f(int i) {
        int a = i >> 2, b = i & 3; return 8 * a * (a + 1) + 4 * (a + 1) * b; } };
    constexpr int LSZ = RO::f(PADM);
    constexpr int YOFF = LSZ;               // patch rows live after the packed L
    constexpr int UN = LSZ + PADM * YSTR;   // padded: tile reads up to row PADM-1
    __shared__ __align__(16) float SU[UN];
    __shared__ __align__(16) float cbuf[2][64];
    __shared__ __align__(16) float rdiag[PADM];
    __shared__ float wsh[M];
    __shared__ int gix[M];
    const int b = blockIdx.x, n = blockIdx.y;
    const int t = threadIdx.x;
    const int lane = t & 63, wv = t >> 6;
    if (t < M) gix[t] = idx[(size_t)(n * NB + b) * M + t];
    __syncthreads();
    const float* im = y + (size_t)n * IMG_SZ;
    const float* xim = xsrc + (size_t)n * IMG_SZ;
    // --- stage Gram source rows (R1: Ys at YOFF; R2: Xs at 0) ---
    {
        const float* src = R2 ? xim : im;
        float* dst = R2 ? &SU[0] : &SU[YOFF];
        for (int e = t; e < M * YSTR; e += 128) {
            int i = e / YSTR, ch = e - i * YSTR;
            float v = 0.f;
            if (ch < NP) {
                int p = gix[i];
                v = src[(p / HP + ch / 7) * IMG_W + (p % HP + ch % 7)];
            }
            dst[i * YSTR + ch] = v;
        }
    }
    __syncthreads();
    const float sg = sigma_p[0];
    const float cns = 49.f * sg * sg;
    // --- tiled Gram: thread t -> 4x4 tile (ti,tj), tj<=ti; acc in registers.
    // Rows >= M read garbage (in-array pad); those entries never written.
    float acc[4][4];
    int ti = 0, tj = 0;
    const bool gact = (t < NT);
    if (gact) {
        ti = (int)((sqrtf(8.f * t + 1.f) - 1.f) * 0.5f);
        while ((ti + 1) * (ti + 2) / 2 <= t) ++ti;
        while (ti * (ti + 1) / 2 > t) --ti;
        tj = t - ti * (ti + 1) / 2;
        const float* base = R2 ? &SU[0] : &SU[YOFF];
        const float* Ar = base + 4 * ti * YSTR;
        const float* Br = base + 4 * tj * YSTR;
#pragma unroll
        for (int r = 0; r < 4; ++r)
#pragma unroll
            for (int s = 0; s < 4; ++s) acc[r][s] = 0.f;
#pragma unroll
        for (int q = 0; q < 13; ++q) {
            float4 av[4], bv[4];
#pragma unroll
            for (int r = 0; r < 4; ++r) av[r] = *(const float4*)(Ar + r * YSTR + 4 * q);
#pragma unroll
            for (int s = 0; s < 4; ++s) bv[s] = *(const float4*)(Br + s * YSTR + 4 * q);
#pragma unroll
            for (int r = 0; r < 4; ++r)
#pragma unroll
                for (int s = 0; s < 4; ++s) {
                    acc[r][s] = fmaf(av[r].x, bv[s].x, acc[r][s]);
                    acc[r][s] = fmaf(av[r].y, bv[s].y, acc[r][s]);
                    acc[r][s] = fmaf(av[r].z, bv[s].z, acc[r][s]);
                    acc[r][s] = fmaf(av[r].w, bv[s].w, acc[r][s]);
                }
        }
    }
    __syncthreads();  // all Gram reads complete before A overlays Xs region
    // --- write packed A (guarded); R2: stage Ys (overwrites dead Xs tail) ---
    if (gact) {
#pragma unroll
        for (int r = 0; r < 4; ++r)
#pragma unroll
            for (int s = 0; s < 4; ++s) {
                int gi2 = 4 * ti + r, gj2 = 4 * tj + s;
                if (gj2 <= gi2 && gi2 < M) {
                    float v = acc[r][s];
                    if (R2 && gi2 == gj2) v += cns;
                    SU[RO::f(gi2) + gj2] = v;
                }
            }
    }
    if (R2) {
        for (int e = t; e < M * YSTR; e += 128) {
            int i = e / YSTR, ch = e - i * YSTR;
            float v = 0.f;
            if (ch < NP) {
                int p = gix[i];
                v = im[(p / HP + ch / 7) * IMG_W + (p % HP + ch % 7)];
            }
            SU[YOFF + i * YSTR + ch] = v;
        }
    }
    __syncthreads();
    const bool isId = (wv == 0) && (lane < M);
    const bool isY = (wv == 1) && (lane < NP);
    const int ch = (wv == 1 && lane < NP) ? lane : 0;
    float bb[PADM];
    // wave1: prefetch solve RHS NOW (overlaps wave0's Cholesky; SU rows are
    // stable — Cholesky touches only the packed-L region).
    if (wv == 1) {
#pragma unroll
        for (int i = 0; i < PADM; ++i) bb[i] = (i < M) ? SU[YOFF + i * YSTR + ch] : 0.f;
    }
    // --- wave0: register-row Cholesky (d^2 form), zero barriers, ping-pong
    // early-column publish to hide the cbuf read-after-write round-trip ---
    if (wv == 0) {
        float g[PADM];
        if (lane < M) {
#pragma unroll
            for (int j = 0; j < PADM; ++j) {
                if (j >= M) g[j] = 0.f;
                else g[j] = (j <= lane) ? SU[RO::f(lane) + j] : SU[RO::f(j) + lane];
            }
        } else {
#pragma unroll
            for (int j = 0; j < PADM; ++j) g[j] = (j == lane) ? 1.f : 0.f;
        }
        cbuf[0][lane] = g[0];  // prime column 0
#pragma unroll
        for (int k = 0; k < PADM - 1; ++k) {
            const float* cb = cbuf[k & 1];
            float* cn = cbuf[(k + 1) & 1];
            float ivd = 1.f / cb[k];
            float fk = g[k] * ivd;
            // first chunk contains k+1: update it, publish next column early
            constexpr int dummy = 0; (void)dummy;
            const int jb0 = (k + 1) / 4;
            {
                float4 cv = *(const float4*)&cb[4 * jb0];
                if (4 * jb0 + 0 > k) g[4 * jb0 + 0] = fmaf(-fk, cv.x, g[4 * jb0 + 0]);
                if (4 * jb0 + 1 > k) g[4 * jb0 + 1] = fmaf(-fk, cv.y, g[4 * jb0 + 1]);
                if (4 * jb0 + 2 > k) g[4 * jb0 + 2] = fmaf(-fk, cv.z, g[4 * jb0 + 2]);
                if (4 * jb0 + 3 > k) g[4 * jb0 + 3] = fmaf(-fk, cv.w, g[4 * jb0 + 3]);
            }
            cn[lane] = g[k + 1];
#pragma unroll
            for (int jb = jb0 + 1; jb < NCH; ++jb) {
                float4 cv = *(const float4*)&cb[4 * jb];
                g[4 * jb + 0] = fmaf(-fk, cv.x, g[4 * jb + 0]);
                g[4 * jb + 1] = fmaf(-fk, cv.y, g[4 * jb + 1]);
                g[4 * jb + 2] = fmaf(-fk, cv.z, g[4 * jb + 2]);
                g[4 * jb + 3] = fmaf(-fk, cv.w, g[4 * jb + 3]);
            }
        }
        if (lane < PADM) rdiag[lane] = (lane < M) ? 1.f / sqrtf(g[lane]) : 1.f;
        // scale row by rdiag[col], store packed L (only j<=i read by solves)
        if (lane < PADM) {
#pragma unroll
            for (int jb = 0; jb < NCH; ++jb) {
                if (4 * jb <= lane) {
                    float4 rd4 = *(const float4*)&rdiag[4 * jb];
                    float4 o;
                    o.x = g[4 * jb + 0] * rd4.x;
                    o.y = g[4 * jb + 1] * rd4.y;
                    o.z = g[4 * jb + 2] * rd4.z;
                    o.w = g[4 * jb + 3] * rd4.w;
                    *(float4*)&SU[RO::f(lane) + 4 * jb] = o;
                }
            }
        }
        // wave0 RHS = identity column (registers only; after g is dead)
#pragma unroll
        for (int i = 0; i < PADM; ++i) bb[i] = (i == lane) ? 1.f : 0.f;
    }
    __syncthreads();
    // --- solves: wave0 lane -> identity col (weights), wave1 lane -> Y col ---
    // forward: L z = b, 4-wide chunks; all L loads wave-uniform broadcasts
#pragma unroll
    for (int ck = 0; ck < NCH; ++ck) {
        const int i0 = 4 * ck;
        float L10 = SU[RO::f(4 * ck + 1) + 4 * ck];
        float L20 = SU[RO::f(4 * ck + 2) + 4 * ck], L21 = SU[RO::f(4 * ck + 2) + 4 * ck + 1];
        float L30 = SU[RO::f(4 * ck + 3) + 4 * ck], L31 = SU[RO::f(4 * ck + 3) + 4 * ck + 1],
              L32 = SU[RO::f(4 * ck + 3) + 4 * ck + 2];
        float b0 = bb[i0] * rdiag[i0];
        float b1 = (bb[i0 + 1] - L10 * b0) * rdiag[i0 + 1];
        float b2 = (bb[i0 + 2] - L20 * b0 - L21 * b1) * rdiag[i0 + 2];
        float b3 = (bb[i0 + 3] - L30 * b0 - L31 * b1 - L32 * b2) * rdiag[i0 + 3];
        bb[i0] = b0; bb[i0 + 1] = b1; bb[i0 + 2] = b2; bb[i0 + 3] = b3;
#pragma unroll
        for (int j = 4 * ck + 4; j < PADM; ++j) {
            float4 L4 = *(const float4*)&SU[RO::f(j) + 4 * ck];
            bb[j] = fmaf(-L4.x, b0, fmaf(-L4.y, b1, fmaf(-L4.z, b2, fmaf(-L4.w, b3, bb[j]))));
        }
        if ((ck & 3) == 3) asm volatile("" ::: "memory");  // 4-chunk hoist window
    }
    // backward: L^T x = z, row sweeps as aligned float4 + compile-time tails
#pragma unroll
    for (int i = PADM - 1; i >= 0; --i) {
        float bbi = bb[i] * rdiag[i];
        bb[i] = bbi;
#pragma unroll
        for (int qb = 0; qb < i / 4; ++qb) {
            float4 L4 = *(const float4*)&SU[RO::f(i) + 4 * qb];
            bb[4 * qb + 0] = fmaf(-L4.x, bbi, bb[4 * qb + 0]);
            bb[4 * qb + 1] = fmaf(-L4.y, bbi, bb[4 * qb + 1]);
            bb[4 * qb + 2] = fmaf(-L4.z, bbi, bb[4 * qb + 2]);
            bb[4 * qb + 3] = fmaf(-L4.w, bbi, bb[4 * qb + 3]);
        }
#pragma unroll
        for (int j = i & ~3; j < i; ++j)
            bb[j] = fmaf(-SU[RO::f(i) + j], bbi, bb[j]);
        if ((i & 15) == 0) asm volatile("" ::: "memory");  // 16-row hoist window
    }
    // --- weights (theta symmetric via identity columns) ---
    float wloc = 0.f;
    if (isId) {
        float s2 = 0.f;
#pragma unroll
        for (int i = 0; i < M; ++i) {
            float th = ((i == lane) ? 1.f : 0.f) - cns * bb[i];
            s2 = fmaf(th, th, s2);
        }
        s2 = fminf(fmaxf(s2, 1.f / (float)M), 1.f);
        wloc = 1.f / s2;
        wsh[lane] = wloc;
    }
    if (!AGGP && isY) {
#pragma unroll
        for (int i = 0; i < M; ++i)
            SU[YOFF + i * YSTR + ch] = fmaf(-cns, bb[i], SU[YOFF + i * YSTR + ch]);
    }
    __syncthreads();
    if (AGGP) {
        // per-PATCH scatter: ~7-way contention, lane-coalesced Xacc lines
        if (isId) atomicAdd(&Wacc[(size_t)n * NPAT + gix[lane]], wloc);
        if (isY) {
#pragma unroll
            for (int i = 0; i < M; ++i) {
                float xv = fmaf(-cns, bb[i], SU[YOFF + i * YSTR + ch]);
                atomicAdd(&Xacc[((size_t)n * NPAT + gix[i]) * NP + ch], xv * wsh[i]);
            }
        }
    } else {
        float* aA = accPix + (size_t)n * IMG_SZ * 2;
        for (int e = t; e < M * NP; e += 128) {
            int i = e / NP, c2 = e % NP;
            int p = gix[i];
            int pix = (p / HP + c2 / 7) * IMG_W + (p % HP + c2 % 7);
            float wi = wsh[i];
            atomicAdd(&aA[pix * 2], SU[YOFF + i * YSTR + c2] * wi);
            atomicAdd(&aA[pix * 2 + 1], wi);
        }
    }
}

extern "C" void kernel_launch(void* const* d_in, const int* in_sizes, int n_in,
                              void* d_out, int out_size, void* d_ws, size_t ws_size,
                              hipStream_t stream) {
    const float* y = (const float*)d_in[0];
    const float* sigma = (const float*)d_in[1];
    float* out = (float*)d_out;

    char* ws = (char*)d_ws;
    size_t off = 0;
    auto carve = [&](size_t bytes) {
        void* p = ws + off;
        off += (bytes + 255) & ~(size_t)255;
        return p;
    };
    int* idx1 = (int*)carve((size_t)NIMG * NB * 18 * sizeof(int));
    int* idx2 = (int*)carve((size_t)NIMG * NB * 55 * sizeof(int));
    float* accPix = (float*)carve((size_t)NIMG * IMG_SZ * 2 * sizeof(float));
    float* den1 = (float*)carve((size_t)NIMG * IMG_SZ * sizeof(float));
    // PATCH-mode accumulators: X then W contiguous (zeroed together)
    const size_t xw_floats = (size_t)NIMG * NPAT * (NP + 1);
    float* Xacc = (float*)carve(xw_floats * sizeof(float));
    float* Wacc = Xacc + (size_t)NIMG * NPAT * NP;
    const bool patchMode = (off <= ws_size);

    const int imgTotal = NIMG * IMG_SZ;

    if (patchMode) {
        const int xwTotal = (int)xw_floats;
        // Round 1: M1=18
        zero_kernel<<<(xwTotal + 255) / 256, 256, 0, stream>>>(Xacc, xwTotal);
        bm_kernel<18><<<dim3(16, 64, NIMG), 256, 0, stream>>>(y, idx1);
        denoise_kernel<18, false, true><<<dim3(NB, NIMG), 128, 0, stream>>>(
            y, y, idx1, sigma, accPix, Xacc, Wacc);
        fold_div_kernel<<<dim3(32, 32, NIMG), 256, 0, stream>>>(Xacc, Wacc, den1);
        // Round 2: M2=55
        zero_kernel<<<(xwTotal + 255) / 256, 256, 0, stream>>>(Xacc, xwTotal);
        bm_kernel<55><<<dim3(16, 64, NIMG), 256, 0, stream>>>(den1, idx2);
        denoise_kernel<55, true, true><<<dim3(NB, NIMG), 128, 0, stream>>>(
            y, den1, idx2, sigma, accPix, Xacc, Wacc);
        fold_div_kernel<<<dim3(32, 32, NIMG), 256, 0, stream>>>(Xacc, Wacc, out);
    } else {
        const int accTotal = NIMG * IMG_SZ * 2;
        // Round 1: M1=18
        zero_kernel<<<(accTotal + 255) / 256, 256, 0, stream>>>(accPix, accTotal);
        bm_kernel<18><<<dim3(16, 64, NIMG), 256, 0, stream>>>(y, idx1);
        denoise_kernel<18, false, false><<<dim3(NB, NIMG), 128, 0, stream>>>(
            y, y, idx1, sigma, accPix, Xacc, Wacc);
        div_kernel<<<(imgTotal + 255) / 256, 256, 0, stream>>>(accPix, den1, imgTotal);
        // Round 2: M2=55
        zero_kernel<<<(accTotal + 255) / 256, 256, 0, stream>>>(accPix, accTotal);
        bm_kernel<55><<<dim3(16, 64, NIMG), 256, 0, stream>>>(den1, idx2);
        denoise_kernel<55, true, false><<<dim3(NB, NIMG), 128, 0, stream>>>(
            y, den1, idx2, sigma, accPix, Xacc, Wacc);
        div_kernel<<<(imgTotal + 255) / 256, 256, 0, stream>>>(accPix, out, imgTotal);
    }
}

// Round 16
// 913.178 us; speedup vs baseline: 1.7133x; 1.0107x over previous
//
#include <hip/hip_runtime.h>
#include <math.h>

#define IMG_H 256
#define IMG_W 256
#define IMG_SZ (IMG_H * IMG_W)
#define NP 49      /* C*p*p patch vector length */
#define HP 250     /* H - p + 1 */
#define NPAT 62500 /* HP*HP patches per image */
#define NB 4096    /* groups per image = 64*64 */
#define NCAND 1369 /* 37*37 */
#define VRAD 18
#define CENTER (VRAD * 37 + VRAD)
#define NIMG 2
#define YSTR 52    /* patch row stride: 208B, 16B aligned */
#define WSTR 55    /* bm window stride: odd -> conflict-free */
/* CUMULATIVE bank-phase row swizzle: +4 floats every 8 rows (monotone, no
   overlap — fixes r15's modular-phase wrap bug). Rows 8k apart differ by
   4k mod 32 banks, splitting the stride-52 period-8 bank-class collisions. */
#define ROWOFF(i) ((i) * YSTR + 4 * ((i) >> 3))

// Map aligned-patch coordinates (253x253, after align_corners with s=4 on a
// 250x250 grid) to original patch coordinates. Returns false for inf slots.
__device__ __forceinline__ bool align_map(int r, int c, int& ro, int& co) {
    if (r < 0 || r > 252 || c < 0 || c > 252) return false;
    if (r == 252) {
        if (c == 252) { ro = 249; co = 249; return true; }
        if (c <= 248 && (c & 3) == 0) { ro = 249; co = c; return true; }
        return false;
    }
    if (c == 252) {
        if (r <= 248 && (r & 3) == 0) { ro = r; co = 249; return true; }
        return false;
    }
    if (r >= 250 || c >= 250) return false;
    if (r == 249) {
        if (c == 249) return false;
        if ((c & 3) == 0) return false;
        ro = 249; co = c; return true;
    }
    if (c == 249) {
        if ((r & 3) == 0) return false;
        ro = r; co = 249; return true;
    }
    ro = r; co = c; return true;
}

// PIXEL-mode: acc holds interleaved (num, weight) pairs per pixel.
__global__ void div_kernel(const float* __restrict__ acc, float* __restrict__ out, int total) {
    int i = blockIdx.x * blockDim.x + threadIdx.x;
    if (i < total) out[i] = acc[2 * i] / acc[2 * i + 1];
}

// PATCH-mode fold: one block per 8x8 pixel tile. Stage the 14x14 covering
// patch rows into LDS (coalesced), then 4 threads/pixel split the 7 ki rows
// and quad-reduce.
__global__ __launch_bounds__(256) void fold_div_kernel(const float* __restrict__ Xacc,
                                                       const float* __restrict__ Wacc,
                                                       float* __restrict__ out) {
    __shared__ __align__(16) float Xs[196 * 49];
    __shared__ float Ws[196];
    const int tc = blockIdx.x, tr = blockIdx.y, n = blockIdx.z;
    const int r0 = tr * 8, c0 = tc * 8;
    const int pr0 = r0 - 6, pc0 = c0 - 6;
    const int t = threadIdx.x;
    const float* Xn = Xacc + (size_t)n * NPAT * NP;
    const float* Wn = Wacc + (size_t)n * NPAT;
    for (int e = t; e < 196 * 49; e += 256) {
        int pr_l = e / 686, rem = e - pr_l * 686;
        int pc_l = rem / 49, ch = rem - pc_l * 49;
        int pr = pr0 + pr_l, pc = pc0 + pc_l;
        float v = 0.f;
        if (pr >= 0 && pr < HP && pc >= 0 && pc < HP)
            v = Xn[(size_t)(pr * HP + pc) * NP + ch];
        Xs[e] = v;
    }
    for (int e = t; e < 196; e += 256) {
        int pr = pr0 + e / 14, pc = pc0 + e % 14;
        float v = 0.f;
        if (pr >= 0 && pr < HP && pc >= 0 && pc < HP) v = Wn[pr * HP + pc];
        Ws[e] = v;
    }
    __syncthreads();
    const int p = t >> 2, part = t & 3;
    const int prx = p >> 3, pcx = p & 7;  // pixel within tile
    float num = 0.f, den = 0.f;
    const int ki0 = part * 2;
    const int kiN = (part == 3) ? 1 : 2;
    for (int kk = 0; kk < kiN; ++kk) {
        int ki = ki0 + kk;
        int pr_l = prx + 6 - ki;
#pragma unroll
        for (int kj = 0; kj < 7; ++kj) {
            int pc_l = pcx + 6 - kj;
            num += Xs[pr_l * 686 + pc_l * 49 + ki * 7 + kj];
            den += Ws[pr_l * 14 + pc_l];
        }
    }
    num += __shfl_xor(num, 1);
    den += __shfl_xor(den, 1);
    num += __shfl_xor(num, 2);
    den += __shfl_xor(den, 2);
    if (part == 0)
        out[(size_t)n * IMG_SZ + (r0 + prx) * IMG_W + (c0 + pcx)] = num / den;
}

// 4 reference patches per 256-thread block (one wave each), sharing one staged
// union window. refp in registers; center forced during fill; selection via
// barrier-free shfl butterfly over per-lane top-2 caches.
template <int M>
__global__ __launch_bounds__(256) void bm_kernel(const float* __restrict__ img,
                                                 int* __restrict__ idx_out) {
    __shared__ float win[43 * WSTR];
    __shared__ float dist[4][NCAND];
    const int llb = blockIdx.x, kk = blockIdx.y, n = blockIdx.z;
    const float* im = img + (size_t)n * IMG_SZ;
    const int t = threadIdx.x;
    const int w = t >> 6, lane = t & 63;
    const int ll = 4 * llb + w;
    const int rr = (kk < 63) ? 4 * kk : 249;
    const int cc = (ll < 63) ? 4 * ll : 249;
    const int ar0 = 4 * kk, ac0 = 4 * ll;
    const int acb = 16 * llb;
    const int row0 = max(0, ar0 - VRAD), col0 = max(0, acb - VRAD);
    const int row1 = min(IMG_H - 1, ar0 + VRAD + 6);
    const int col1 = min(IMG_W - 1, acb + 12 + VRAD + 6);
    const int nr = row1 - row0 + 1, nc = col1 - col0 + 1;
    for (int e = t; e < nr * nc; e += 256) {
        int r = e / nc, c = e % nc;
        win[r * WSTR + c] = im[(row0 + r) * IMG_W + col0 + c];
    }
    __syncthreads();
    float rf[NP];
    {
        const float* rb = &win[(rr - row0) * WSTR + (cc - col0)];
#pragma unroll
        for (int ki = 0; ki < 7; ++ki)
#pragma unroll
            for (int kj = 0; kj < 7; ++kj) rf[ki * 7 + kj] = rb[ki * WSTR + kj];
    }
    float* dw = dist[w];
    for (int cand = lane; cand < NCAND; cand += 64) {
        const int dr = cand / 37 - VRAD, dc = cand % 37 - VRAD;
        int ro, co;
        float d;
        if (align_map(ar0 + dr, ac0 + dc, ro, co)) {
            const float* base = &win[(ro - row0) * WSTR + (co - col0)];
            float s = 0.f;
#pragma unroll
            for (int ki = 0; ki < 7; ++ki)
#pragma unroll
                for (int kj = 0; kj < 7; ++kj) {
                    float df = base[ki * WSTR + kj] - rf[ki * 7 + kj] + 1e-6f;
                    s = fmaf(df, df, s);
                }
            d = sqrtf(s);
        } else {
            d = INFINITY;
        }
        if (cand == CENTER) d = -1.0f;  // center always wins sel 0
        dw[cand] = d;
    }
    __syncthreads();
    // per-lane top-2 over the strided bucket (ascending scan => ties keep low idx)
    float v1 = INFINITY, v2 = INFINITY;
    int i1 = NCAND, i2 = NCAND;
    for (int c = lane; c < NCAND; c += 64) {
        float v = dw[c];
        if (v < v1) { v2 = v1; i2 = i1; v1 = v; i1 = c; }
        else if (v < v2) { v2 = v; i2 = c; }
    }
    int* out = idx_out + (size_t)((n * 64 + kk) * 64 + ll) * M;
    for (int sel = 0; sel < M; ++sel) {
        float gv = v1;
        int gi = i1;
#pragma unroll
        for (int off = 32; off; off >>= 1) {
            float vv = __shfl_xor(gv, off);
            int ii = __shfl_xor(gi, off);
            if (vv < gv || (vv == gv && ii < gi)) { gv = vv; gi = ii; }
        }
        if (lane == 0) {
            int dr = gi / 37 - VRAD, dc = gi % 37 - VRAD;
            out[sel] = min(rr + dr, 249) * HP + min(cc + dc, 249);
        }
        if ((gi & 63) == lane) {  // owner pops its cache; rescan only if exhausted
            dw[gi] = INFINITY;
            v1 = v2; i1 = i2; v2 = INFINITY; i2 = NCAND;
            if (i1 == NCAND) {
                for (int c = lane; c < NCAND; c += 64) {
                    float v = dw[c];
                    if (v < v1) { v2 = v1; i2 = i1; v1 = v; i1 = c; }
                    else if (v < v2) { v2 = v; i2 = c; }
                }
            }
        }
    }
}

// 128 threads (2 waves) per group. theta = I - c*A^-1 in BOTH rounds.
// LDS union SU = [packed-L | patch rows]; patch-row bases carry a CUMULATIVE
// float4 bank-phase swizzle (ROWOFF, monotone — no row overlap) breaking the
// period-8 bank-class collisions of stride-52 rows. Gram: 2-D register tiling
// (4x4 tile per thread). Cholesky: wave0-only register rows (d^2 form) with
// ping-pong early-column publish; wave1 prefetches its solve RHS concurrently.
// Solve: wave0 = M identity cols (weights), wave1 = 49 Y cols (X_hat);
// uniform broadcast float4 L reads at constexpr packed offsets; 4-chunk/16-row
// hoist windows. Epilogue: per-PATCH atomics (AGGP) or per-pixel fallback.
template <int M, bool R2, bool AGGP>
__global__ __launch_bounds__(128, 2) void denoise_kernel(
    const float* __restrict__ y, const float* __restrict__ xsrc,
    const int* __restrict__ idx, const float* __restrict__ sigma_p,
    float* __restrict__ accPix, float* __restrict__ Xacc, float* __restrict__ Wacc) {
    constexpr int PADM = (M + 3) & ~3;  // 56 for M=55, 20 for M=18
    constexpr int NCH = PADM / 4;
    constexpr int TR = PADM / 4;            // Gram tile-rows
    constexpr int NT = TR * (TR + 1) / 2;   // 105 / 15 tiles
    // packed row offset (floats), each row 16B aligned: sum_{k<i} roundup4(k+1)
    struct RO { static constexpr int f(int i) {
        int a = i >> 2, b = i & 3; return 8 * a * (a + 1) + 4 * (a + 1) * b; } };
    constexpr int LSZ = RO::f(PADM);
    constexpr int YOFF = LSZ;                          // patch rows after packed L
    constexpr int UN = LSZ + ROWOFF(PADM) + 16;        // swizzled rows + pad
    __shared__ __align__(16) float SU[UN];
    __shared__ __align__(16) float cbuf[2][64];
    __shared__ __align__(16) float rdiag[PADM];
    __shared__ float wsh[M];
    __shared__ int gix[M];
    const int b = blockIdx.x, n = blockIdx.y;
    const int t = threadIdx.x;
    const int lane = t & 63, wv = t >> 6;
    if (t < M) gix[t] = idx[(size_t)(n * NB + b) * M + t];
    __syncthreads();
    const float* im = y + (size_t)n * IMG_SZ;
    const float* xim = xsrc + (size_t)n * IMG_SZ;
    // --- stage Gram source rows (R1: Ys at YOFF; R2: Xs at 0) ---
    {
        const float* src = R2 ? xim : im;
        float* dst = R2 ? &SU[0] : &SU[YOFF];
        for (int e = t; e < M * YSTR; e += 128) {
            int i = e / YSTR, ch = e - i * YSTR;
            float v = 0.f;
            if (ch < NP) {
                int p = gix[i];
                v = src[(p / HP + ch / 7) * IMG_W + (p % HP + ch % 7)];
            }
            dst[ROWOFF(i) + ch] = v;
        }
    }
    __syncthreads();
    const float sg = sigma_p[0];
    const float cns = 49.f * sg * sg;
    // --- tiled Gram: thread t -> 4x4 tile (ti,tj), tj<=ti; acc in registers.
    // Rows >= M read garbage (in-array pad); those entries never written.
    float acc[4][4];
    int ti = 0, tj = 0;
    const bool gact = (t < NT);
    if (gact) {
        ti = (int)((sqrtf(8.f * t + 1.f) - 1.f) * 0.5f);
        while ((ti + 1) * (ti + 2) / 2 <= t) ++ti;
        while (ti * (ti + 1) / 2 > t) --ti;
        tj = t - ti * (ti + 1) / 2;
        const float* base = R2 ? &SU[0] : &SU[YOFF];
        int ra[4], rb[4];
#pragma unroll
        for (int r = 0; r < 4; ++r) {
            ra[r] = ROWOFF(4 * ti + r);
            rb[r] = ROWOFF(4 * tj + r);
        }
#pragma unroll
        for (int r = 0; r < 4; ++r)
#pragma unroll
            for (int s = 0; s < 4; ++s) acc[r][s] = 0.f;
#pragma unroll
        for (int q = 0; q < 13; ++q) {
            float4 av[4], bv[4];
#pragma unroll
            for (int r = 0; r < 4; ++r) av[r] = *(const float4*)(base + ra[r] + 4 * q);
#pragma unroll
            for (int s = 0; s < 4; ++s) bv[s] = *(const float4*)(base + rb[s] + 4 * q);
#pragma unroll
            for (int r = 0; r < 4; ++r)
#pragma unroll
                for (int s = 0; s < 4; ++s) {
                    acc[r][s] = fmaf(av[r].x, bv[s].x, acc[r][s]);
                    acc[r][s] = fmaf(av[r].y, bv[s].y, acc[r][s]);
                    acc[r][s] = fmaf(av[r].z, bv[s].z, acc[r][s]);
                    acc[r][s] = fmaf(av[r].w, bv[s].w, acc[r][s]);
                }
        }
    }
    __syncthreads();  // all Gram reads complete before A overlays Xs region
    // --- write packed A (guarded); R2: stage Ys (overwrites dead Xs tail) ---
    if (gact) {
#pragma unroll
        for (int r = 0; r < 4; ++r)
#pragma unroll
            for (int s = 0; s < 4; ++s) {
                int gi2 = 4 * ti + r, gj2 = 4 * tj + s;
                if (gj2 <= gi2 && gi2 < M) {
                    float v = acc[r][s];
                    if (R2 && gi2 == gj2) v += cns;
                    SU[RO::f(gi2) + gj2] = v;
                }
            }
    }
    if (R2) {
        for (int e = t; e < M * YSTR; e += 128) {
            int i = e / YSTR, ch = e - i * YSTR;
            float v = 0.f;
            if (ch < NP) {
                int p = gix[i];
                v = im[(p / HP + ch / 7) * IMG_W + (p % HP + ch % 7)];
            }
            SU[YOFF + ROWOFF(i) + ch] = v;
        }
    }
    __syncthreads();
    const bool isId = (wv == 0) && (lane < M);
    const bool isY = (wv == 1) && (lane < NP);
    const int ch = (wv == 1 && lane < NP) ? lane : 0;
    float bb[PADM];
    // wave1: prefetch solve RHS NOW (overlaps wave0's Cholesky; SU rows are
    // stable — Cholesky touches only the packed-L region).
    if (wv == 1) {
#pragma unroll
        for (int i = 0; i < PADM; ++i)
            bb[i] = (i < M) ? SU[YOFF + ROWOFF(i) + ch] : 0.f;
    }
    // --- wave0: register-row Cholesky (d^2 form), zero barriers, ping-pong
    // early-column publish to hide the cbuf read-after-write round-trip ---
    if (wv == 0) {
        float g[PADM];
        if (lane < M) {
#pragma unroll
            for (int j = 0; j < PADM; ++j) {
                if (j >= M) g[j] = 0.f;
                else g[j] = (j <= lane) ? SU[RO::f(lane) + j] : SU[RO::f(j) + lane];
            }
        } else {
#pragma unroll
            for (int j = 0; j < PADM; ++j) g[j] = (j == lane) ? 1.f : 0.f;
        }
        cbuf[0][lane] = g[0];  // prime column 0
#pragma unroll
        for (int k = 0; k < PADM - 1; ++k) {
            const float* cb = cbuf[k & 1];
            float* cn = cbuf[(k + 1) & 1];
            float ivd = 1.f / cb[k];
            float fk = g[k] * ivd;
            // first chunk contains k+1: update it, publish next column early
            const int jb0 = (k + 1) / 4;
            {
                float4 cv = *(const float4*)&cb[4 * jb0];
                if (4 * jb0 + 0 > k) g[4 * jb0 + 0] = fmaf(-fk, cv.x, g[4 * jb0 + 0]);
                if (4 * jb0 + 1 > k) g[4 * jb0 + 1] = fmaf(-fk, cv.y, g[4 * jb0 + 1]);
                if (4 * jb0 + 2 > k) g[4 * jb0 + 2] = fmaf(-fk, cv.z, g[4 * jb0 + 2]);
                if (4 * jb0 + 3 > k) g[4 * jb0 + 3] = fmaf(-fk, cv.w, g[4 * jb0 + 3]);
            }
            cn[lane] = g[k + 1];
#pragma unroll
            for (int jb = jb0 + 1; jb < NCH; ++jb) {
                float4 cv = *(const float4*)&cb[4 * jb];
                g[4 * jb + 0] = fmaf(-fk, cv.x, g[4 * jb + 0]);
                g[4 * jb + 1] = fmaf(-fk, cv.y, g[4 * jb + 1]);
                g[4 * jb + 2] = fmaf(-fk, cv.z, g[4 * jb + 2]);
                g[4 * jb + 3] = fmaf(-fk, cv.w, g[4 * jb + 3]);
            }
        }
        if (lane < PADM) rdiag[lane] = (lane < M) ? 1.f / sqrtf(g[lane]) : 1.f;
        // scale row by rdiag[col], store packed L (only j<=i read by solves)
        if (lane < PADM) {
#pragma unroll
            for (int jb = 0; jb < NCH; ++jb) {
                if (4 * jb <= lane) {
                    float4 rd4 = *(const float4*)&rdiag[4 * jb];
                    float4 o;
                    o.x = g[4 * jb + 0] * rd4.x;
                    o.y = g[4 * jb + 1] * rd4.y;
                    o.z = g[4 * jb + 2] * rd4.z;
                    o.w = g[4 * jb + 3] * rd4.w;
                    *(float4*)&SU[RO::f(lane) + 4 * jb] = o;
                }
            }
        }
        // wave0 RHS = identity column (registers only; after g is dead)
#pragma unroll
        for (int i = 0; i < PADM; ++i) bb[i] = (i == lane) ? 1.f : 0.f;
    }
    __syncthreads();
    // --- solves: wave0 lane -> identity col (weights), wave1 lane -> Y col ---
    // forward: L z = b, 4-wide chunks; all L loads wave-uniform broadcasts
#pragma unroll
    for (int ck = 0; ck < NCH; ++ck) {
        const int i0 = 4 * ck;
        float L10 = SU[RO::f(4 * ck + 1) + 4 * ck];
        float L20 = SU[RO::f(4 * ck + 2) + 4 * ck], L21 = SU[RO::f(4 * ck + 2) + 4 * ck + 1];
        float L30 = SU[RO::f(4 * ck + 3) + 4 * ck], L31 = SU[RO::f(4 * ck + 3) + 4 * ck + 1],
              L32 = SU[RO::f(4 * ck + 3) + 4 * ck + 2];
        float b0 = bb[i0] * rdiag[i0];
        float b1 = (bb[i0 + 1] - L10 * b0) * rdiag[i0 + 1];
        float b2 = (bb[i0 + 2] - L20 * b0 - L21 * b1) * rdiag[i0 + 2];
        float b3 = (bb[i0 + 3] - L30 * b0 - L31 * b1 - L32 * b2) * rdiag[i0 + 3];
        bb[i0] = b0; bb[i0 + 1] = b1; bb[i0 + 2] = b2; bb[i0 + 3] = b3;
#pragma unroll
        for (int j = 4 * ck + 4; j < PADM; ++j) {
            float4 L4 = *(const float4*)&SU[RO::f(j) + 4 * ck];
            bb[j] = fmaf(-L4.x, b0, fmaf(-L4.y, b1, fmaf(-L4.z, b2, fmaf(-L4.w, b3, bb[j]))));
        }
        if ((ck & 3) == 3) asm volatile("" ::: "memory");  // 4-chunk hoist window
    }
    // backward: L^T x = z, row sweeps as aligned float4 + compile-time tails
#pragma unroll
    for (int i = PADM - 1; i >= 0; --i) {
        float bbi = bb[i] * rdiag[i];
        bb[i] = bbi;
#pragma unroll
        for (int qb = 0; qb < i / 4; ++qb) {
            float4 L4 = *(const float4*)&SU[RO::f(i) + 4 * qb];
            bb[4 * qb + 0] = fmaf(-L4.x, bbi, bb[4 * qb + 0]);
            bb[4 * qb + 1] = fmaf(-L4.y, bbi, bb[4 * qb + 1]);
            bb[4 * qb + 2] = fmaf(-L4.z, bbi, bb[4 * qb + 2]);
            bb[4 * qb + 3] = fmaf(-L4.w, bbi, bb[4 * qb + 3]);
        }
#pragma unroll
        for (int j = i & ~3; j < i; ++j)
            bb[j] = fmaf(-SU[RO::f(i) + j], bbi, bb[j]);
        if ((i & 15) == 0) asm volatile("" ::: "memory");  // 16-row hoist window
    }
    // --- weights (theta symmetric via identity columns) ---
    float wloc = 0.f;
    if (isId) {
        float s2 = 0.f;
#pragma unroll
        for (int i = 0; i < M; ++i) {
            float th = ((i == lane) ? 1.f : 0.f) - cns * bb[i];
            s2 = fmaf(th, th, s2);
        }
        s2 = fminf(fmaxf(s2, 1.f / (float)M), 1.f);
        wloc = 1.f / s2;
        wsh[lane] = wloc;
    }
    if (!AGGP && isY) {
#pragma unroll
        for (int i = 0; i < M; ++i)
            SU[YOFF + ROWOFF(i) + ch] = fmaf(-cns, bb[i], SU[YOFF + ROWOFF(i) + ch]);
    }
    __syncthreads();
    if (AGGP) {
        // per-PATCH scatter: ~7-way contention, lane-coalesced Xacc lines
        if (isId) atomicAdd(&Wacc[(size_t)n * NPAT + gix[lane]], wloc);
        if (isY) {
#pragma unroll
            for (int i = 0; i < M; ++i) {
                float xv = fmaf(-cns, bb[i], SU[YOFF + ROWOFF(i) + ch]);
                atomicAdd(&Xacc[((size_t)n * NPAT + gix[i]) * NP + ch], xv * wsh[i]);
            }
        }
    } else {
        float* aA = accPix + (size_t)n * IMG_SZ * 2;
        for (int e = t; e < M * NP; e += 128) {
            int i = e / NP, c2 = e % NP;
            int p = gix[i];
            int pix = (p / HP + c2 / 7) * IMG_W + (p % HP + c2 % 7);
            float wi = wsh[i];
            atomicAdd(&aA[pix * 2], SU[YOFF + ROWOFF(i) + c2] * wi);
            atomicAdd(&aA[pix * 2 + 1], wi);
        }
    }
}

extern "C" void kernel_launch(void* const* d_in, const int* in_sizes, int n_in,
                              void* d_out, int out_size, void* d_ws, size_t ws_size,
                              hipStream_t stream) {
    const float* y = (const float*)d_in[0];
    const float* sigma = (const float*)d_in[1];
    float* out = (float*)d_out;

    char* ws = (char*)d_ws;
    size_t off = 0;
    auto carve = [&](size_t bytes) {
        void* p = ws + off;
        off += (bytes + 255) & ~(size_t)255;
        return p;
    };
    int* idx1 = (int*)carve((size_t)NIMG * NB * 18 * sizeof(int));
    int* idx2 = (int*)carve((size_t)NIMG * NB * 55 * sizeof(int));
    float* accPix = (float*)carve((size_t)NIMG * IMG_SZ * 2 * sizeof(float));
    float* den1 = (float*)carve((size_t)NIMG * IMG_SZ * sizeof(float));
    // PATCH-mode accumulators: X then W contiguous (zeroed together)
    const size_t xw_floats = (size_t)NIMG * NPAT * (NP + 1);
    float* Xacc = (float*)carve(xw_floats * sizeof(float));
    float* Wacc = Xacc + (size_t)NIMG * NPAT * NP;
    const bool patchMode = (off <= ws_size);

    const int imgTotal = NIMG * IMG_SZ;

    if (patchMode) {
        // Round 1: M1=18
        hipMemsetAsync(Xacc, 0, xw_floats * sizeof(float), stream);
        bm_kernel<18><<<dim3(16, 64, NIMG), 256, 0, stream>>>(y, idx1);
        denoise_kernel<18, false, true><<<dim3(NB, NIMG), 128, 0, stream>>>(
            y, y, idx1, sigma, accPix, Xacc, Wacc);
        fold_div_kernel<<<dim3(32, 32, NIMG), 256, 0, stream>>>(Xacc, Wacc, den1);
        // Round 2: M2=55
        hipMemsetAsync(Xacc, 0, xw_floats * sizeof(float), stream);
        bm_kernel<55><<<dim3(16, 64, NIMG), 256, 0, stream>>>(den1, idx2);
        denoise_kernel<55, true, true><<<dim3(NB, NIMG), 128, 0, stream>>>(
            y, den1, idx2, sigma, accPix, Xacc, Wacc);
        fold_div_kernel<<<dim3(32, 32, NIMG), 256, 0, stream>>>(Xacc, Wacc, out);
    } else {
        const size_t accBytes = (size_t)NIMG * IMG_SZ * 2 * sizeof(float);
        // Round 1: M1=18
        hipMemsetAsync(accPix, 0, accBytes, stream);
        bm_kernel<18><<<dim3(16, 64, NIMG), 256, 0, stream>>>(y, idx1);
        denoise_kernel<18, false, false><<<dim3(NB, NIMG), 128, 0, stream>>>(
            y, y, idx1, sigma, accPix, Xacc, Wacc);
        div_kernel<<<(imgTotal + 255) / 256, 256, 0, stream>>>(accPix, den1, imgTotal);
        // Round 2: M2=55
        hipMemsetAsync(accPix, 0, accBytes, stream);
        bm_kernel<55><<<dim3(16, 64, NIMG), 256, 0, stream>>>(den1, idx2);
        denoise_kernel<55, true, false><<<dim3(NB, NIMG), 128, 0, stream>>>(
            y, den1, idx2, sigma, accPix, Xacc, Wacc);
        div_kernel<<<(imgTotal + 255) / 256, 256, 0, stream>>>(accPix, out, imgTotal);
    }
}